// Round 10
// baseline (313.628 us; speedup 1.0000x reference)
//
#include <hip/hip_runtime.h>
#include <hip/hip_bf16.h>
#include <hip/hip_cooperative_groups.h>

namespace cg = cooperative_groups;

// Problem constants (B,H,W,C) = (4,56,56,256), nh=8, K=7, lr=4, hd=32
#define BD 4
#define HD_ 56
#define WD 56
#define CD 256
#define NH 8
#define KW 7
#define LR 4
#define HDIM 32
#define MB (HD_*WD)              // 3136 rows per batch
#define NROWS (BD*MB)            // 12544 total rows
#define QK_PER_B (HD_*WD*32)     // 100352
#define V_PER_B  (HD_*WD*256)    // 802816
#define GRID_B 512               // co-resident guaranteed (>=2 blocks/CU at VGPR<=256)

typedef short short8 __attribute__((ext_vector_type(8)));   // 8 bf16 (4 VGPRs)
typedef float floatx4 __attribute__((ext_vector_type(4)));  // MFMA C/D

static __device__ inline ushort f2bf(float f) {
    __hip_bfloat16 h = __float2bfloat16(f);
    return *(ushort*)&h;
}
static __device__ inline float bf2f(uint h16) {
    union { uint u; float f; } c; c.u = h16 << 16; return c.f;
}
static __device__ inline float bf2f_hi(uint u) {
    union { uint v; float f; } c; c.v = u & 0xffff0000u; return c.f;
}

typedef const __attribute__((address_space(1))) void* gp1_t;
typedef __attribute__((address_space(3))) void* sp3_t;
static __device__ __forceinline__ void glds16(const void* g, void* s) {
    __builtin_amdgcn_global_load_lds((gp1_t)g, (sp3_t)s, 16, 0, 0);
}

struct Params {
    const float *x, *Wq, *bq, *Wk, *bk, *Wv, *bv, *rpb, *Wp, *bp;
    ushort *xb, *WpkT, *WpT, *Qb, *Kb, *Vb, *Ab;
    float *pb;
    float *out;
};

// shared-memory union across phases (max 24576 B -> many blocks/CU possible;
// we only need the guaranteed 2)
union SharedU {
    struct { ushort As[128 * 64]; ushort Bs[64 * 64]; } g;                     // 24576 qkv
    struct { ushort As[64 * 64];  ushort Bs[64 * 64]; } o;                     // 16384 out
    struct { ushort Pl[32 * 168]; ushort Vt[32 * 168];
             float4 Ksf[140]; float Rs[169]; float invS[32]; } a;              // 24544 attn
};

// ---- proven 128x64 BK=64 GEMM core (R1-R5 hardware-verified) ----
static __device__ __forceinline__ void gemm_core_128x64(
    const ushort* __restrict__ Ag, const ushort* __restrict__ Bg,
    ushort* As, ushort* Bs, int m0, int n0, int t, floatx4 (&acc)[4][2])
{
    const int lane = t & 63, w = t >> 6;
    const int lx = lane & 7, ly = lane >> 3;
    const int koff = (lx ^ ly) << 3;
    const int col = lane & 15, quad = lane >> 4;
    const int swz = (col & 7) << 4;
    const int wm = w >> 1, wn = w & 1;
    char* Ac = (char*)As;
    char* Bc = (char*)Bs;

    for (int k0 = 0; k0 < 256; k0 += 64) {
        __syncthreads();
#pragma unroll
        for (int l = 0; l < 4; ++l) {
            int c = (w << 2) + l;
            int row = (c << 3) + ly;
            glds16(&Ag[(m0 + row) * 256 + k0 + koff], &As[c << 9]);
        }
#pragma unroll
        for (int l = 0; l < 2; ++l) {
            int c = (w << 1) + l;
            int row = (c << 3) + ly;
            glds16(&Bg[(n0 + row) * 256 + k0 + koff], &Bs[c << 9]);
        }
        __syncthreads();
#pragma unroll
        for (int kk = 0; kk < 2; ++kk) {
            const int kx = ((kk << 6) + (quad << 4)) ^ swz;
            short8 b0 = *(short8*)(Bc + ((wn << 5) + col) * 128 + kx);
            short8 b1 = *(short8*)(Bc + ((wn << 5) + 16 + col) * 128 + kx);
#pragma unroll
            for (int mt = 0; mt < 4; ++mt) {
                short8 a = *(short8*)(Ac + ((wm << 6) + (mt << 4) + col) * 128 + kx);
                acc[mt][0] = __builtin_amdgcn_mfma_f32_16x16x32_bf16(a, b0, acc[mt][0], 0, 0, 0);
                acc[mt][1] = __builtin_amdgcn_mfma_f32_16x16x32_bf16(a, b1, acc[mt][1], 0, 0, 0);
            }
        }
    }
}

// ==================== MONO-KERNEL: all 4 phases, 1 dispatch ====================
// Theory: the 4-kernel chain spends ~20 us in inter-dispatch gaps (~5 us per
// boundary; kernel work sums to ~19 us of the measured 39.7 us chain). grid.sync()
// between phases replaces kernel boundaries at ~1-2 us each.
__global__ __launch_bounds__(256, 2) void mono(Params P)
{
    __shared__ SharedU su;
    cg::grid_group grid = cg::this_grid();
    const int t = threadIdx.x;
    const int bid = blockIdx.x;
    const int lane = t & 63, w = t >> 6;
    const int col = lane & 15, quad = lane >> 4;

    // ---------------- P0: prep (grid-strided; 549184 items) ----------------
#pragma unroll 1
    for (int it = 0; it < 5; ++it) {
        int idx = bid * 256 + t + it * (GRID_B * 256);
        if (idx < 401408) {
            float4 f0 = *(const float4*)&P.x[idx * 8];
            float4 f1 = *(const float4*)&P.x[idx * 8 + 4];
            union { ushort h[8]; uint4 u; } p;
            p.h[0] = f2bf(f0.x); p.h[1] = f2bf(f0.y); p.h[2] = f2bf(f0.z); p.h[3] = f2bf(f0.w);
            p.h[4] = f2bf(f1.x); p.h[5] = f2bf(f1.y); p.h[6] = f2bf(f1.z); p.h[7] = f2bf(f1.w);
            *(uint4*)&P.xb[idx * 8] = p.u;
        } else if (idx < 401408 + 81920) {
            int j = idx - 401408;
            int n = j >> 8, k = j & 255;
            float v;
            if (n < 32)       v = P.Wq[k * 32 + n];
            else if (n < 64)  v = P.Wk[k * 32 + (n - 32)];
            else              v = P.Wv[k * 256 + (n - 64)];
            P.WpkT[j] = f2bf(v);
        } else if (idx < 401408 + 81920 + 65536) {
            int j = idx - (401408 + 81920);
            int n = j >> 8, k = j & 255;
            P.WpT[j] = f2bf(P.Wp[k * 256 + n]);
        } else if (idx < 401408 + 81920 + 65536 + 320) {
            int n = idx - (401408 + 81920 + 65536);
            P.pb[n] = (n < 32) ? P.bq[n] : (n < 64) ? P.bk[n - 32] : P.bv[n - 64];
        }
    }
    grid.sync();

    // ---------------- P1: QKV projection (490 tiles of 128x64) --------------
#pragma unroll 1
    for (int tile = bid; tile < 490; tile += GRID_B) {
        int n0 = (tile % 5) * 64, m0 = (tile / 5) * 128;
        floatx4 acc[4][2] = {};
        gemm_core_128x64(P.xb, P.WpkT, su.g.As, su.g.Bs, m0, n0, t, acc);

        const int wm = w >> 1, wn = w & 1;
#pragma unroll
        for (int mt = 0; mt < 4; ++mt) {
#pragma unroll
            for (int nt = 0; nt < 2; ++nt) {
                int gn = n0 + (wn << 5) + (nt << 4) + col;
                float bias = P.pb[gn];
#pragma unroll
                for (int rg = 0; rg < 4; ++rg) {
                    int m = m0 + (wm << 6) + (mt << 4) + (quad << 2) + rg;
                    ushort hh = f2bf(acc[mt][nt][rg] + bias);
                    if (gn < 32)        P.Qb[m * 32 + gn] = hh;
                    else if (gn < 64)   P.Kb[m * 32 + (gn - 32)] = hh;
                    else                P.Vb[m * 256 + (gn - 64)] = hh;
                }
            }
        }
    }
    grid.sync();

    // ---------------- P2: NATTEN attention (3136 tiles of 4x8 q) ------------
    {
        const int q = t >> 3, p = t & 7;
        const int qi = q >> 3, qj = q & 7;
        const int wmA = w & 1, wnA = w >> 1;
        const float scale = 0.17677669529663687f;
#pragma unroll 1
        for (int tile = bid; tile < 3136; tile += GRID_B) {
            const int tj = tile % 7;
            const int rest = tile / 7;
            const int ti = rest % 14;
            const int z  = rest / 14;
            const int h = z & 7, b = z >> 3;
            const int i0 = ti * 4, j0 = tj * 8;
            const int rs = min(max(i0 - 3, 0), HD_ - 10);
            const int cs = min(max(j0 - 3, 0), WD - 14);

            const ushort* kb = P.Kb + (size_t)b * QK_PER_B + h * (HD_ * WD * LR);
            const ushort* vb = P.Vb + (size_t)b * V_PER_B + h * (HD_ * WD * HDIM);

#pragma unroll
            for (int it = 0; it < 3; ++it) {
                int idx = t + (it << 8);
                if (idx < 672) {
                    *(uint4*)&su.a.Pl[idx << 3] = make_uint4(0, 0, 0, 0);
                    *(uint4*)&su.a.Vt[idx << 3] = make_uint4(0, 0, 0, 0);
                }
            }
            __syncthreads();

            if (t < 140) {
                int r = t / 14, c = t % 14;
                uint2 kr = *(const uint2*)&kb[(rs + r) * (WD * LR) + (cs + c) * LR];
                su.a.Ksf[t] = make_float4(bf2f(kr.x & 0xffff), bf2f_hi(kr.x),
                                          bf2f(kr.y & 0xffff), bf2f_hi(kr.y));
            }
            if (t < 169) su.a.Rs[t] = P.rpb[h * 169 + t];
#pragma unroll
            for (int it = 0; it < 3; ++it) {
                int idx = t + (it << 8);
                if (idx < 560) {
                    int oct = idx / 140, pos = idx % 140;
                    int r = pos / 14, c = pos % 14;
                    union { uint4 u; ushort hh[8]; } vv;
                    vv.u = *(const uint4*)&vb[(rs + r) * (WD * HDIM) + (cs + c) * HDIM + oct * 8];
                    ushort* cp = &su.a.Vt[(oct * 8) * 168 + pos];
#pragma unroll
                    for (int e = 0; e < 8; ++e) cp[e * 168] = vv.hh[e];
                }
            }

            const int i = i0 + qi, j = j0 + qj;
            uint2 qr2 = *(const uint2*)&P.Qb[(size_t)b * QK_PER_B + h * (HD_ * WD * LR) + i * (WD * LR) + j * LR];
            __syncthreads();

            const int sh = min(max(i - 3, 0), HD_ - KW);
            const int sw = min(max(j - 3, 0), WD - KW);
            const int oh = sh - rs, ow = sw - cs;
            const int rb0 = (sh - i + 6) * 13 + (sw - j + 6);
            float qx = bf2f(qr2.x & 0xffff) * scale, qy = bf2f_hi(qr2.x) * scale;
            float qz = bf2f(qr2.y & 0xffff) * scale, qw = bf2f_hi(qr2.y) * scale;

            float sum = 0.f;
            if (p < 7) {
                int kpos  = (oh + p) * 14 + ow;
                int rbase = rb0 + p * 13;
                ushort* prow = &su.a.Pl[q * 168 + kpos];
#pragma unroll
                for (int kw = 0; kw < 7; ++kw) {
                    float4 kf = su.a.Ksf[kpos + kw];
                    float d = su.a.Rs[rbase + kw];
                    d = fmaf(qx, kf.x, d);
                    d = fmaf(qy, kf.y, d);
                    d = fmaf(qz, kf.z, d);
                    d = fmaf(qw, kf.w, d);
                    float e = __expf(d);
                    sum += e;
                    prow[kw] = f2bf(e);
                }
            }
            sum += __shfl_xor(sum, 1);
            sum += __shfl_xor(sum, 2);
            sum += __shfl_xor(sum, 4);
            if (p == 0) su.a.invS[q] = 1.0f / sum;
            __syncthreads();

            floatx4 acc = {0.f, 0.f, 0.f, 0.f};
            const ushort* arow = &su.a.Pl[(wmA * 16 + col) * 168];
            const ushort* brow = &su.a.Vt[(wnA * 16 + col) * 168];
#pragma unroll
            for (int s = 0; s < 5; ++s) {
                int ko = s * 32 + quad * 8;
                short8 a  = *(const short8*)(arow + ko);
                short8 bb = *(const short8*)(brow + ko);
                acc = __builtin_amdgcn_mfma_f32_16x16x32_bf16(a, bb, acc, 0, 0, 0);
            }

#pragma unroll
            for (int rg = 0; rg < 4; ++rg) {
                int qq = wmA * 16 + quad * 4 + rg;
                float iv = su.a.invS[qq];
                int ii = i0 + (qq >> 3), jj = j0 + (qq & 7);
                P.Ab[(((b * HD_ + ii) * WD + jj)) * CD + h * HDIM + wnA * 16 + col] = f2bf(acc[rg] * iv);
            }
            __syncthreads();   // LDS reuse isolation across tiles (R7-proven)
        }
    }
    grid.sync();

    // ---------------- P3: output projection (784 tiles of 64x64) ------------
    {
        const int lx = lane & 7, ly = lane >> 3;
        const int koff = (lx ^ ly) << 3;
        const int swz = (col & 7) << 4;
        const int wm = w >> 1, wn = w & 1;
        char* Ac = (char*)su.o.As;
        char* Bc = (char*)su.o.Bs;
#pragma unroll 1
        for (int tile = bid; tile < 784; tile += GRID_B) {
            int n0 = (tile % 4) * 64, m0 = (tile / 4) * 64;
            floatx4 acc[2][2] = {};

            for (int k0 = 0; k0 < 256; k0 += 64) {
                __syncthreads();
#pragma unroll
                for (int l = 0; l < 2; ++l) {
                    int c = (w << 1) + l;
                    int row = (c << 3) + ly;
                    glds16(&P.Ab[(m0 + row) * 256 + k0 + koff], &su.o.As[c << 9]);
                    glds16(&P.WpT[(n0 + row) * 256 + k0 + koff], &su.o.Bs[c << 9]);
                }
                __syncthreads();
#pragma unroll
                for (int kk = 0; kk < 2; ++kk) {
                    const int kx = ((kk << 6) + (quad << 4)) ^ swz;
                    short8 b0 = *(short8*)(Bc + ((wn << 5) + col) * 128 + kx);
                    short8 b1 = *(short8*)(Bc + ((wn << 5) + 16 + col) * 128 + kx);
#pragma unroll
                    for (int mt = 0; mt < 2; ++mt) {
                        short8 a = *(short8*)(Ac + ((wm << 5) + (mt << 4) + col) * 128 + kx);
                        acc[mt][0] = __builtin_amdgcn_mfma_f32_16x16x32_bf16(a, b0, acc[mt][0], 0, 0, 0);
                        acc[mt][1] = __builtin_amdgcn_mfma_f32_16x16x32_bf16(a, b1, acc[mt][1], 0, 0, 0);
                    }
                }
            }

#pragma unroll
            for (int mt = 0; mt < 2; ++mt) {
#pragma unroll
                for (int nt = 0; nt < 2; ++nt) {
                    int gn = n0 + (wn << 5) + (nt << 4) + col;
                    float bias = P.bp[gn];
#pragma unroll
                    for (int rg = 0; rg < 4; ++rg) {
                        int m = m0 + (wm << 5) + (mt << 4) + (quad << 2) + rg;
                        P.out[m * 256 + gn] = acc[mt][nt][rg] + bias;
                    }
                }
            }
        }
    }
}

extern "C" void kernel_launch(void* const* d_in, const int* in_sizes, int n_in,
                              void* d_out, int out_size, void* d_ws, size_t ws_size,
                              hipStream_t stream) {
    // workspace layout — bf16 intermediates; ~21 MB of 256 MiB ws
    ushort* WpkT = (ushort*)d_ws;          // 81920
    ushort* WpT  = WpkT + 81920;           // 65536
    ushort* Ab   = WpT + 65536;            // 3211264
    ushort* Qb   = Ab + 3211264;           // 401408
    ushort* Kb   = Qb + BD * QK_PER_B;     // 401408
    ushort* Vb   = Kb + BD * QK_PER_B;     // 3211264
    ushort* xb   = Vb + BD * V_PER_B;      // 3211264
    float*  pb   = (float*)(xb + 3211264); // 320

    Params P;
    P.x   = (const float*)d_in[0];
    P.Wq  = (const float*)d_in[1];
    P.bq  = (const float*)d_in[2];
    P.Wk  = (const float*)d_in[3];
    P.bk  = (const float*)d_in[4];
    P.Wv  = (const float*)d_in[5];
    P.bv  = (const float*)d_in[6];
    P.rpb = (const float*)d_in[7];
    P.Wp  = (const float*)d_in[8];
    P.bp  = (const float*)d_in[9];
    P.xb = xb; P.WpkT = WpkT; P.WpT = WpT;
    P.Qb = Qb; P.Kb = Kb; P.Vb = Vb; P.Ab = Ab;
    P.pb = pb;
    P.out = (float*)d_out;

    void* kargs[] = { (void*)&P };
    hipLaunchCooperativeKernel((const void*)mono, dim3(GRID_B), dim3(256),
                               kargs, 0, stream);
}

// Round 12
// 122.944 us; speedup vs baseline: 2.5510x; 2.5510x over previous
//
#include <hip/hip_runtime.h>
#include <hip/hip_bf16.h>

// Problem constants (B,H,W,C) = (4,56,56,256), nh=8, K=7, lr=4, hd=32
#define BD 4
#define HD_ 56
#define WD 56
#define CD 256
#define NH 8
#define KW 7
#define LR 4
#define HDIM 32
#define MB (HD_*WD)              // 3136 rows per batch
#define NROWS (BD*MB)            // 12544 total rows
#define QK_PER_B (HD_*WD*32)     // 100352
#define V_PER_B  (HD_*WD*256)    // 802816

typedef short short8 __attribute__((ext_vector_type(8)));   // 8 bf16 (4 VGPRs)
typedef float floatx4 __attribute__((ext_vector_type(4)));  // MFMA C/D

static __device__ inline ushort f2bf(float f) {
    __hip_bfloat16 h = __float2bfloat16(f);
    return *(ushort*)&h;
}
static __device__ inline float bf2f(uint h16) {
    union { uint u; float f; } c; c.u = h16 << 16; return c.f;
}
static __device__ inline float bf2f_hi(uint u) {
    union { uint v; float f; } c; c.v = u & 0xffff0000u; return c.f;
}

typedef const __attribute__((address_space(1))) void* gp1_t;
typedef __attribute__((address_space(3))) void* sp3_t;
static __device__ __forceinline__ void glds16(const void* g, void* s) {
    __builtin_amdgcn_global_load_lds((gp1_t)g, (sp3_t)s, 16, 0, 0);
}

// ---------------- K1: QKV projection with INLINE x->bf16 + W gather ---------
// Replaces prep_all + mfma_qkv (one dispatch + one boundary saved; xb/WpkT/pb
// buffers eliminated). Staging is reg-based: fp32 load -> cvt -> ds_write at
// the SAME swizzled offsets the proven glds16 path produced (write-side XOR ==
// read-side XOR). B-tile gathered transposed from Wq/Wk/Wv (fp32 scalar
// gathers; 320 KB source, L2-resident across the 98 m-blocks per n-tile).
// Bias applied inline from bq/bk/bv. Numerics identical to the prep path.
__global__ __launch_bounds__(256) void qkv_fused(
    const float* __restrict__ x,
    const float* __restrict__ Wq, const float* __restrict__ Wk,
    const float* __restrict__ Wv,
    const float* __restrict__ bq, const float* __restrict__ bk,
    const float* __restrict__ bv,
    ushort* __restrict__ Qb, ushort* __restrict__ Kb, ushort* __restrict__ Vb)
{
    __shared__ ushort As[128 * 64];   // 16 KB, swizzled chunks
    __shared__ ushort Bs[64 * 64];    // 8 KB
    const int t = threadIdx.x;
    const int m0 = blockIdx.y * 128, n0 = blockIdx.x * 64;
    const int lane = t & 63, w = t >> 6;
    const int lx = lane & 7, ly = lane >> 3;
    const int koff = (lx ^ ly) << 3;          // element offset within 64-wide row
    const int col = lane & 15, quad = lane >> 4;
    const int swz = (col & 7) << 4;
    const int wm = w >> 1, wn = w & 1;
    char* Ac = (char*)As;
    char* Bc = (char*)Bs;

    floatx4 acc[4][2] = {};

    for (int k0 = 0; k0 < 256; k0 += 64) {
        // ---- reg-stage: load fp32, convert (overlaps prev compute) ----
        uint4 areg[4], breg[2];
#pragma unroll
        for (int l = 0; l < 4; ++l) {
            int c = (w << 2) + l, row = (c << 3) + ly;
            float4 f0 = *(const float4*)&x[(m0 + row) * 256 + k0 + koff];
            float4 f1 = *(const float4*)&x[(m0 + row) * 256 + k0 + koff + 4];
            union { ushort h[8]; uint4 u; } pk;
            pk.h[0] = f2bf(f0.x); pk.h[1] = f2bf(f0.y); pk.h[2] = f2bf(f0.z); pk.h[3] = f2bf(f0.w);
            pk.h[4] = f2bf(f1.x); pk.h[5] = f2bf(f1.y); pk.h[6] = f2bf(f1.z); pk.h[7] = f2bf(f1.w);
            areg[l] = pk.u;
        }
#pragma unroll
        for (int l = 0; l < 2; ++l) {
            int c = (w << 1) + l, nr = (c << 3) + ly;
            int gn = n0 + nr;
            union { ushort h[8]; uint4 u; } pk;
#pragma unroll
            for (int e = 0; e < 8; ++e) {
                int k = k0 + koff + e;
                float v;
                if (gn < 32)       v = Wq[k * 32 + gn];
                else if (gn < 64)  v = Wk[k * 32 + (gn - 32)];
                else               v = Wv[k * 256 + (gn - 64)];
                pk.h[e] = f2bf(v);
            }
            breg[l] = pk.u;
        }
        __syncthreads();                      // prev compute's LDS reads done
#pragma unroll
        for (int l = 0; l < 4; ++l) {
            int c = (w << 2) + l;
            *(uint4*)(Ac + (c << 10) + lane * 16) = areg[l];
        }
#pragma unroll
        for (int l = 0; l < 2; ++l) {
            int c = (w << 1) + l;
            *(uint4*)(Bc + (c << 10) + lane * 16) = breg[l];
        }
        __syncthreads();                      // staging visible
        // ---- compute: identical to proven gemm_core_128x64 ----
#pragma unroll
        for (int kk = 0; kk < 2; ++kk) {
            const int kx = ((kk << 6) + (quad << 4)) ^ swz;
            short8 b0 = *(short8*)(Bc + ((wn << 5) + col) * 128 + kx);
            short8 b1 = *(short8*)(Bc + ((wn << 5) + 16 + col) * 128 + kx);
#pragma unroll
            for (int mt = 0; mt < 4; ++mt) {
                short8 a = *(short8*)(Ac + ((wm << 6) + (mt << 4) + col) * 128 + kx);
                acc[mt][0] = __builtin_amdgcn_mfma_f32_16x16x32_bf16(a, b0, acc[mt][0], 0, 0, 0);
                acc[mt][1] = __builtin_amdgcn_mfma_f32_16x16x32_bf16(a, b1, acc[mt][1], 0, 0, 0);
            }
        }
    }

#pragma unroll
    for (int mt = 0; mt < 4; ++mt) {
#pragma unroll
        for (int nt = 0; nt < 2; ++nt) {
            int gn = n0 + (wn << 5) + (nt << 4) + col;
            float bias = (gn < 32) ? bq[gn] : (gn < 64) ? bk[gn - 32] : bv[gn - 64];
#pragma unroll
            for (int rg = 0; rg < 4; ++rg) {
                int m = m0 + (wm << 6) + (mt << 4) + (quad << 2) + rg;
                ushort h = f2bf(acc[mt][nt][rg] + bias);
                if (gn < 32)        Qb[m * 32 + gn] = h;
                else if (gn < 64)   Kb[m * 32 + (gn - 32)] = h;
                else                Vb[m * 256 + (gn - 64)] = h;
            }
        }
    }
}

// ---------------- K2: NATTEN attention v4 (proven) + WpT-prep prologue ------
// Prologue: grid-stride conversion of Wp -> WpT (65536 items over 3136 blocks,
// disjoint writes, consumed only after the next kernel boundary). No barrier
// needed; LDS untouched by it.
__global__ __launch_bounds__(256) void natten_attn4(
    const ushort* __restrict__ Qb, const ushort* __restrict__ Kb,
    const ushort* __restrict__ Vb, const float* __restrict__ rpb,
    const float* __restrict__ Wp, ushort* __restrict__ WpT,
    ushort* __restrict__ Ab)
{
    __shared__ __align__(16) ushort Pl[32 * 168];   // 10752 B  P[q][key]
    __shared__ __align__(16) ushort Vt[32 * 168];   // 10752 B  V^T[ch][key]
    __shared__ float4 Ksf[140];                     // 2240 B
    __shared__ float  Rs[169];                      // 676 B
    __shared__ float  invS[32];                     // 128 B

    const int tj = blockIdx.x, ti = blockIdx.y;
    const int h = blockIdx.z & 7, b = blockIdx.z >> 3;
    const int t = threadIdx.x;

    // --- WpT prep (side job) ---
    {
        int fb = tj + 7 * (ti + 14 * blockIdx.z);
        int idx = fb * 256 + t;
        if (idx < 65536) {
            int n = idx >> 8, k = idx & 255;
            WpT[idx] = f2bf(Wp[k * 256 + n]);
        }
    }

    const int i0 = ti * 4, j0 = tj * 8;
    const int rs = min(max(i0 - 3, 0), HD_ - 10);
    const int cs = min(max(j0 - 3, 0), WD - 14);

    const ushort* kb = Kb + (size_t)b * QK_PER_B + h * (HD_ * WD * LR);
    const ushort* vb = Vb + (size_t)b * V_PER_B + h * (HD_ * WD * HDIM);

#pragma unroll
    for (int it = 0; it < 3; ++it) {
        int idx = t + (it << 8);
        if (idx < 672) {
            *(uint4*)&Pl[idx << 3] = make_uint4(0, 0, 0, 0);
            *(uint4*)&Vt[idx << 3] = make_uint4(0, 0, 0, 0);
        }
    }
    __syncthreads();

    if (t < 140) {
        int r = t / 14, c = t % 14;
        uint2 kr = *(const uint2*)&kb[(rs + r) * (WD * LR) + (cs + c) * LR];
        Ksf[t] = make_float4(bf2f(kr.x & 0xffff), bf2f_hi(kr.x),
                             bf2f(kr.y & 0xffff), bf2f_hi(kr.y));
    }
    if (t < 169) Rs[t] = rpb[h * 169 + t];
#pragma unroll
    for (int it = 0; it < 3; ++it) {
        int idx = t + (it << 8);
        if (idx < 560) {
            int oct = idx / 140, pos = idx % 140;
            int r = pos / 14, c = pos % 14;
            union { uint4 u; ushort hh[8]; } vv;
            vv.u = *(const uint4*)&vb[(rs + r) * (WD * HDIM) + (cs + c) * HDIM + oct * 8];
            ushort* cp = &Vt[(oct * 8) * 168 + pos];
#pragma unroll
            for (int e = 0; e < 8; ++e) cp[e * 168] = vv.hh[e];
        }
    }

    const int q  = t >> 3, p = t & 7;
    const int qi = q >> 3, qj = q & 7;
    const int i = i0 + qi, j = j0 + qj;
    uint2 qr2 = *(const uint2*)&Qb[(size_t)b * QK_PER_B + h * (HD_ * WD * LR) + i * (WD * LR) + j * LR];
    __syncthreads();

    const int sh = min(max(i - 3, 0), HD_ - KW);
    const int sw = min(max(j - 3, 0), WD - KW);
    const int oh = sh - rs, ow = sw - cs;
    const int rb0 = (sh - i + 6) * 13 + (sw - j + 6);
    const float scale = 0.17677669529663687f;
    float qx = bf2f(qr2.x & 0xffff) * scale, qy = bf2f_hi(qr2.x) * scale;
    float qz = bf2f(qr2.y & 0xffff) * scale, qw = bf2f_hi(qr2.y) * scale;

    float sum = 0.f;
    if (p < 7) {
        int kpos  = (oh + p) * 14 + ow;
        int rbase = rb0 + p * 13;
        ushort* prow = &Pl[q * 168 + kpos];
#pragma unroll
        for (int kw = 0; kw < 7; ++kw) {
            float4 kf = Ksf[kpos + kw];
            float d = Rs[rbase + kw];
            d = fmaf(qx, kf.x, d);
            d = fmaf(qy, kf.y, d);
            d = fmaf(qz, kf.z, d);
            d = fmaf(qw, kf.w, d);
            float e = __expf(d);
            sum += e;
            prow[kw] = f2bf(e);
        }
    }
    sum += __shfl_xor(sum, 1);
    sum += __shfl_xor(sum, 2);
    sum += __shfl_xor(sum, 4);
    if (p == 0) invS[q] = 1.0f / sum;
    __syncthreads();

    const int lane = t & 63, w = t >> 6;
    const int col = lane & 15, quad = lane >> 4;
    const int wm = w & 1, wn = w >> 1;
    floatx4 acc = {0.f, 0.f, 0.f, 0.f};
    const ushort* arow = &Pl[(wm * 16 + col) * 168];
    const ushort* brow = &Vt[(wn * 16 + col) * 168];
#pragma unroll
    for (int s = 0; s < 5; ++s) {
        int ko = s * 32 + quad * 8;
        short8 a  = *(const short8*)(arow + ko);
        short8 bb = *(const short8*)(brow + ko);
        acc = __builtin_amdgcn_mfma_f32_16x16x32_bf16(a, bb, acc, 0, 0, 0);
    }

#pragma unroll
    for (int rg = 0; rg < 4; ++rg) {
        int qq = wm * 16 + quad * 4 + rg;
        float iv = invS[qq];
        int ii = i0 + (qq >> 3), jj = j0 + (qq & 7);
        Ab[(((b * HD_ + ii) * WD + jj)) * CD + h * HDIM + wn * 16 + col] = f2bf(acc[rg] * iv);
    }
}

// ---------------- K3: output projection, 64x64 tiles (proven R5) ------------
__global__ __launch_bounds__(256) void mfma_out64(
    const ushort* __restrict__ Ag, const ushort* __restrict__ Bt,
    const float* __restrict__ bp, float* __restrict__ out)
{
    __shared__ ushort As[64 * 64];   // 8 KB
    __shared__ ushort Bs[64 * 64];   // 8 KB
    const int t = threadIdx.x;
    const int m0 = blockIdx.y * 64, n0 = blockIdx.x * 64;
    const int lane = t & 63, w = t >> 6;
    const int lx = lane & 7, ly = lane >> 3;
    const int koff = (lx ^ ly) << 3;
    const int col = lane & 15, quad = lane >> 4;
    const int swz = (col & 7) << 4;
    const int wm = w >> 1, wn = w & 1;
    char* Ac = (char*)As;
    char* Bc = (char*)Bs;
    floatx4 acc[2][2] = {};

    for (int k0 = 0; k0 < 256; k0 += 64) {
        __syncthreads();
#pragma unroll
        for (int l = 0; l < 2; ++l) {
            int c = (w << 1) + l;
            int row = (c << 3) + ly;
            glds16(&Ag[(m0 + row) * 256 + k0 + koff], &As[c << 9]);
            glds16(&Bt[(n0 + row) * 256 + k0 + koff], &Bs[c << 9]);
        }
        __syncthreads();
#pragma unroll
        for (int kk = 0; kk < 2; ++kk) {
            const int kx = ((kk << 6) + (quad << 4)) ^ swz;
            short8 b0 = *(short8*)(Bc + ((wn << 5) + col) * 128 + kx);
            short8 b1 = *(short8*)(Bc + ((wn << 5) + 16 + col) * 128 + kx);
#pragma unroll
            for (int mt = 0; mt < 2; ++mt) {
                short8 a = *(short8*)(Ac + ((wm << 5) + (mt << 4) + col) * 128 + kx);
                acc[mt][0] = __builtin_amdgcn_mfma_f32_16x16x32_bf16(a, b0, acc[mt][0], 0, 0, 0);
                acc[mt][1] = __builtin_amdgcn_mfma_f32_16x16x32_bf16(a, b1, acc[mt][1], 0, 0, 0);
            }
        }
    }

#pragma unroll
    for (int mt = 0; mt < 2; ++mt) {
#pragma unroll
        for (int nt = 0; nt < 2; ++nt) {
            int gn = n0 + (wn << 5) + (nt << 4) + col;
            float bias = bp[gn];
#pragma unroll
            for (int rg = 0; rg < 4; ++rg) {
                int m = m0 + (wm << 5) + (mt << 4) + (quad << 2) + rg;
                out[m * 256 + gn] = acc[mt][nt][rg] + bias;
            }
        }
    }
}

extern "C" void kernel_launch(void* const* d_in, const int* in_sizes, int n_in,
                              void* d_out, int out_size, void* d_ws, size_t ws_size,
                              hipStream_t stream) {
    const float* x   = (const float*)d_in[0];
    const float* Wq  = (const float*)d_in[1];
    const float* bq  = (const float*)d_in[2];
    const float* Wk  = (const float*)d_in[3];
    const float* bk  = (const float*)d_in[4];
    const float* Wv  = (const float*)d_in[5];
    const float* bv  = (const float*)d_in[6];
    const float* rpb = (const float*)d_in[7];
    const float* Wp  = (const float*)d_in[8];
    const float* bp  = (const float*)d_in[9];
    float* out = (float*)d_out;

    // workspace layout — bf16 intermediates; ~14.6 MB (xb/WpkT/pb eliminated)
    ushort* WpT = (ushort*)d_ws;           // 65536
    ushort* Ab  = WpT + 65536;             // 3211264
    ushort* Qb  = Ab + 3211264;            // 401408
    ushort* Kb  = Qb + BD * QK_PER_B;      // 401408
    ushort* Vb  = Kb + BD * QK_PER_B;      // 3211264

    qkv_fused<<<dim3(5, NROWS / 128), 256, 0, stream>>>(
        x, Wq, Wk, Wv, bq, bk, bv, Qb, Kb, Vb);

    natten_attn4<<<dim3(7, 14, 32), 256, 0, stream>>>(
        Qb, Kb, Vb, rpb, Wp, WpT, Ab);

    mfma_out64<<<dim3(4, 196), 256, 0, stream>>>(Ab, WpT, bp, out);
}

// Round 13
// 115.489 us; speedup vs baseline: 2.7157x; 1.0646x over previous
//
#include <hip/hip_runtime.h>
#include <hip/hip_bf16.h>

// Problem constants (B,H,W,C) = (4,56,56,256), nh=8, K=7, lr=4, hd=32
#define BD 4
#define HD_ 56
#define WD 56
#define CD 256
#define NH 8
#define KW 7
#define LR 4
#define HDIM 32
#define MB (HD_*WD)              // 3136 rows per batch
#define NROWS (BD*MB)            // 12544 total rows
#define QK_PER_B (HD_*WD*32)     // 100352
#define V_PER_B  (HD_*WD*256)    // 802816

typedef short short8 __attribute__((ext_vector_type(8)));   // 8 bf16 (4 VGPRs)
typedef float floatx4 __attribute__((ext_vector_type(4)));  // MFMA C/D

static __device__ inline ushort f2bf(float f) {
    __hip_bfloat16 h = __float2bfloat16(f);
    return *(ushort*)&h;
}
static __device__ inline float bf2f(uint h16) {
    union { uint u; float f; } c; c.u = h16 << 16; return c.f;
}
static __device__ inline float bf2f_hi(uint u) {
    union { uint v; float f; } c; c.v = u & 0xffff0000u; return c.f;
}

typedef const __attribute__((address_space(1))) void* gp1_t;
typedef __attribute__((address_space(3))) void* sp3_t;
static __device__ __forceinline__ void glds16(const void* g, void* s) {
    __builtin_amdgcn_global_load_lds((gp1_t)g, (sp3_t)s, 16, 0, 0);
}

// ---------------- prep: WEIGHTS ONLY (x->bf16 moved into qkv) ---------------
// 81920 (WpkT) + 65536 (WpT) + 320 (pb) = 147776 items, ~1 MB traffic.
__global__ __launch_bounds__(256) void prep_w(
    const float* __restrict__ Wq, const float* __restrict__ Wk,
    const float* __restrict__ Wv, const float* __restrict__ bq,
    const float* __restrict__ bk, const float* __restrict__ bv,
    const float* __restrict__ Wp,
    ushort* __restrict__ WpkT, ushort* __restrict__ WpT, float* __restrict__ pb)
{
    int idx = blockIdx.x * 256 + threadIdx.x;
    if (idx < 81920) {
        int n = idx >> 8, k = idx & 255;
        float v;
        if (n < 32)       v = Wq[k * 32 + n];
        else if (n < 64)  v = Wk[k * 32 + (n - 32)];
        else              v = Wv[k * 256 + (n - 64)];
        WpkT[idx] = f2bf(v);
    } else if (idx < 81920 + 65536) {
        int j = idx - 81920;
        int n = j >> 8, k = j & 255;
        WpT[j] = f2bf(Wp[k * 256 + n]);
    } else if (idx < 81920 + 65536 + 320) {
        int n = idx - (81920 + 65536);
        pb[n] = (n < 32) ? bq[n] : (n < 64) ? bk[n - 32] : bv[n - 64];
    }
}

// ---------------- MFMA GEMM: QKV, A = fp32 x reg-staged inline --------------
// A-path: fp32 load + convert to bf16 in regs (R12-validated numerics),
// ds_write to the SAME swizzled chunk layout glds16 produces. B-path: proven
// glds16 stream from pre-transposed WpkT (the R5 path — R12's scalar W-gather
// regression reverted). Eliminates the xb buffer and its HBM roundtrip.
__global__ __launch_bounds__(256) void mfma_qkv(
    const float* __restrict__ x, const ushort* __restrict__ Bt,
    const float* __restrict__ pb, ushort* __restrict__ Qb,
    ushort* __restrict__ Kb, ushort* __restrict__ Vb)
{
    __shared__ ushort As[128 * 64];   // 16 KB, swizzled chunks
    __shared__ ushort Bs[64 * 64];    // 8 KB
    const int t = threadIdx.x;
    const int m0 = blockIdx.y * 128, n0 = blockIdx.x * 64;
    const int lane = t & 63, w = t >> 6;
    const int lx = lane & 7, ly = lane >> 3;
    const int koff = (lx ^ ly) << 3;
    const int col = lane & 15, quad = lane >> 4;
    const int swz = (col & 7) << 4;
    const int wm = w >> 1, wn = w & 1;
    char* Ac = (char*)As;
    char* Bc = (char*)Bs;

    floatx4 acc[4][2] = {};

    for (int k0 = 0; k0 < 256; k0 += 64) {
        // reg-stage A: fp32 load + cvt (no LDS touched; overlaps prev compute)
        uint4 areg[4];
#pragma unroll
        for (int l = 0; l < 4; ++l) {
            int c = (w << 2) + l, row = (c << 3) + ly;
            float4 f0 = *(const float4*)&x[(m0 + row) * 256 + k0 + koff];
            float4 f1 = *(const float4*)&x[(m0 + row) * 256 + k0 + koff + 4];
            union { ushort h[8]; uint4 u; } pk;
            pk.h[0] = f2bf(f0.x); pk.h[1] = f2bf(f0.y); pk.h[2] = f2bf(f0.z); pk.h[3] = f2bf(f0.w);
            pk.h[4] = f2bf(f1.x); pk.h[5] = f2bf(f1.y); pk.h[6] = f2bf(f1.z); pk.h[7] = f2bf(f1.w);
            areg[l] = pk.u;
        }
        __syncthreads();                      // prev compute's LDS reads done
#pragma unroll
        for (int l = 0; l < 4; ++l) {
            int c = (w << 2) + l;
            *(uint4*)(Ac + (c << 10) + lane * 16) = areg[l];
        }
#pragma unroll
        for (int l = 0; l < 2; ++l) {
            int c = (w << 1) + l;
            int row = (c << 3) + ly;
            glds16(&Bt[(n0 + row) * 256 + k0 + koff], &Bs[c << 9]);
        }
        __syncthreads();                      // ds_writes + glds16 drained
#pragma unroll
        for (int kk = 0; kk < 2; ++kk) {
            const int kx = ((kk << 6) + (quad << 4)) ^ swz;
            short8 b0 = *(short8*)(Bc + ((wn << 5) + col) * 128 + kx);
            short8 b1 = *(short8*)(Bc + ((wn << 5) + 16 + col) * 128 + kx);
#pragma unroll
            for (int mt = 0; mt < 4; ++mt) {
                short8 a = *(short8*)(Ac + ((wm << 6) + (mt << 4) + col) * 128 + kx);
                acc[mt][0] = __builtin_amdgcn_mfma_f32_16x16x32_bf16(a, b0, acc[mt][0], 0, 0, 0);
                acc[mt][1] = __builtin_amdgcn_mfma_f32_16x16x32_bf16(a, b1, acc[mt][1], 0, 0, 0);
            }
        }
    }

#pragma unroll
    for (int mt = 0; mt < 4; ++mt) {
#pragma unroll
        for (int nt = 0; nt < 2; ++nt) {
            int gn = n0 + (wn << 5) + (nt << 4) + col;
            float bias = pb[gn];
#pragma unroll
            for (int rg = 0; rg < 4; ++rg) {
                int m = m0 + (wm << 6) + (mt << 4) + (quad << 2) + rg;
                ushort h = f2bf(acc[mt][nt][rg] + bias);
                if (gn < 32)        Qb[m * 32 + gn] = h;
                else if (gn < 64)   Kb[m * 32 + (gn - 32)] = h;
                else                Vb[m * 256 + (gn - 64)] = h;
            }
        }
    }
}

// ---------------- NATTEN attention v4 (byte-identical R5, 112.15 best) ------
__global__ __launch_bounds__(256) void natten_attn4(
    const ushort* __restrict__ Qb, const ushort* __restrict__ Kb,
    const ushort* __restrict__ Vb, const float* __restrict__ rpb,
    ushort* __restrict__ Ab)
{
    __shared__ __align__(16) ushort Pl[32 * 168];   // 10752 B  P[q][key]
    __shared__ __align__(16) ushort Vt[32 * 168];   // 10752 B  V^T[ch][key]
    __shared__ float4 Ksf[140];                     // 2240 B
    __shared__ float  Rs[169];                      // 676 B
    __shared__ float  invS[32];                     // 128 B

    const int tj = blockIdx.x, ti = blockIdx.y;
    const int h = blockIdx.z & 7, b = blockIdx.z >> 3;
    const int t = threadIdx.x;
    const int i0 = ti * 4, j0 = tj * 8;
    const int rs = min(max(i0 - 3, 0), HD_ - 10);
    const int cs = min(max(j0 - 3, 0), WD - 14);

    const ushort* kb = Kb + (size_t)b * QK_PER_B + h * (HD_ * WD * LR);
    const ushort* vb = Vb + (size_t)b * V_PER_B + h * (HD_ * WD * HDIM);

#pragma unroll
    for (int it = 0; it < 3; ++it) {
        int idx = t + (it << 8);
        if (idx < 672) {
            *(uint4*)&Pl[idx << 3] = make_uint4(0, 0, 0, 0);
            *(uint4*)&Vt[idx << 3] = make_uint4(0, 0, 0, 0);
        }
    }
    __syncthreads();

    if (t < 140) {
        int r = t / 14, c = t % 14;
        uint2 kr = *(const uint2*)&kb[(rs + r) * (WD * LR) + (cs + c) * LR];
        Ksf[t] = make_float4(bf2f(kr.x & 0xffff), bf2f_hi(kr.x),
                             bf2f(kr.y & 0xffff), bf2f_hi(kr.y));
    }
    if (t < 169) Rs[t] = rpb[h * 169 + t];
#pragma unroll
    for (int it = 0; it < 3; ++it) {
        int idx = t + (it << 8);
        if (idx < 560) {
            int oct = idx / 140, pos = idx % 140;
            int r = pos / 14, c = pos % 14;
            union { uint4 u; ushort hh[8]; } vv;
            vv.u = *(const uint4*)&vb[(rs + r) * (WD * HDIM) + (cs + c) * HDIM + oct * 8];
            ushort* cp = &Vt[(oct * 8) * 168 + pos];
#pragma unroll
            for (int e = 0; e < 8; ++e) cp[e * 168] = vv.hh[e];
        }
    }

    const int q  = t >> 3, p = t & 7;
    const int qi = q >> 3, qj = q & 7;
    const int i = i0 + qi, j = j0 + qj;
    uint2 qr2 = *(const uint2*)&Qb[(size_t)b * QK_PER_B + h * (HD_ * WD * LR) + i * (WD * LR) + j * LR];
    __syncthreads();

    const int sh = min(max(i - 3, 0), HD_ - KW);
    const int sw = min(max(j - 3, 0), WD - KW);
    const int oh = sh - rs, ow = sw - cs;
    const int rb0 = (sh - i + 6) * 13 + (sw - j + 6);
    const float scale = 0.17677669529663687f;
    float qx = bf2f(qr2.x & 0xffff) * scale, qy = bf2f_hi(qr2.x) * scale;
    float qz = bf2f(qr2.y & 0xffff) * scale, qw = bf2f_hi(qr2.y) * scale;

    float sum = 0.f;
    if (p < 7) {
        int kpos  = (oh + p) * 14 + ow;
        int rbase = rb0 + p * 13;
        ushort* prow = &Pl[q * 168 + kpos];
#pragma unroll
        for (int kw = 0; kw < 7; ++kw) {
            float4 kf = Ksf[kpos + kw];
            float d = Rs[rbase + kw];
            d = fmaf(qx, kf.x, d);
            d = fmaf(qy, kf.y, d);
            d = fmaf(qz, kf.z, d);
            d = fmaf(qw, kf.w, d);
            float e = __expf(d);
            sum += e;
            prow[kw] = f2bf(e);
        }
    }
    sum += __shfl_xor(sum, 1);
    sum += __shfl_xor(sum, 2);
    sum += __shfl_xor(sum, 4);
    if (p == 0) invS[q] = 1.0f / sum;
    __syncthreads();

    const int lane = t & 63, w = t >> 6;
    const int col = lane & 15, quad = lane >> 4;
    const int wm = w & 1, wn = w >> 1;
    floatx4 acc = {0.f, 0.f, 0.f, 0.f};
    const ushort* arow = &Pl[(wm * 16 + col) * 168];
    const ushort* brow = &Vt[(wn * 16 + col) * 168];
#pragma unroll
    for (int s = 0; s < 5; ++s) {
        int ko = s * 32 + quad * 8;
        short8 a  = *(const short8*)(arow + ko);
        short8 bb = *(const short8*)(brow + ko);
        acc = __builtin_amdgcn_mfma_f32_16x16x32_bf16(a, bb, acc, 0, 0, 0);
    }

#pragma unroll
    for (int rg = 0; rg < 4; ++rg) {
        int qq = wm * 16 + quad * 4 + rg;
        float iv = invS[qq];
        int ii = i0 + (qq >> 3), jj = j0 + (qq & 7);
        Ab[(((b * HD_ + ii) * WD + jj)) * CD + h * HDIM + wn * 16 + col] = f2bf(acc[rg] * iv);
    }
}

// ---------------- MFMA GEMM: output projection, 64x64 (byte-identical R5) ---
__global__ __launch_bounds__(256) void mfma_out64(
    const ushort* __restrict__ Ag, const ushort* __restrict__ Bt,
    const float* __restrict__ bp, float* __restrict__ out)
{
    __shared__ ushort As[64 * 64];   // 8 KB
    __shared__ ushort Bs[64 * 64];   // 8 KB
    const int t = threadIdx.x;
    const int m0 = blockIdx.y * 64, n0 = blockIdx.x * 64;
    const int lane = t & 63, w = t >> 6;
    const int lx = lane & 7, ly = lane >> 3;
    const int koff = (lx ^ ly) << 3;
    const int col = lane & 15, quad = lane >> 4;
    const int swz = (col & 7) << 4;
    const int wm = w >> 1, wn = w & 1;
    char* Ac = (char*)As;
    char* Bc = (char*)Bs;
    floatx4 acc[2][2] = {};

    for (int k0 = 0; k0 < 256; k0 += 64) {
        __syncthreads();
#pragma unroll
        for (int l = 0; l < 2; ++l) {
            int c = (w << 1) + l;
            int row = (c << 3) + ly;
            glds16(&Ag[(m0 + row) * 256 + k0 + koff], &As[c << 9]);
            glds16(&Bt[(n0 + row) * 256 + k0 + koff], &Bs[c << 9]);
        }
        __syncthreads();
#pragma unroll
        for (int kk = 0; kk < 2; ++kk) {
            const int kx = ((kk << 6) + (quad << 4)) ^ swz;
            short8 b0 = *(short8*)(Bc + ((wn << 5) + col) * 128 + kx);
            short8 b1 = *(short8*)(Bc + ((wn << 5) + 16 + col) * 128 + kx);
#pragma unroll
            for (int mt = 0; mt < 2; ++mt) {
                short8 a = *(short8*)(Ac + ((wm << 5) + (mt << 4) + col) * 128 + kx);
                acc[mt][0] = __builtin_amdgcn_mfma_f32_16x16x32_bf16(a, b0, acc[mt][0], 0, 0, 0);
                acc[mt][1] = __builtin_amdgcn_mfma_f32_16x16x32_bf16(a, b1, acc[mt][1], 0, 0, 0);
            }
        }
    }

#pragma unroll
    for (int mt = 0; mt < 2; ++mt) {
#pragma unroll
        for (int nt = 0; nt < 2; ++nt) {
            int gn = n0 + (wn << 5) + (nt << 4) + col;
            float bias = bp[gn];
#pragma unroll
            for (int rg = 0; rg < 4; ++rg) {
                int m = m0 + (wm << 5) + (mt << 4) + (quad << 2) + rg;
                out[m * 256 + gn] = acc[mt][nt][rg] + bias;
            }
        }
    }
}

extern "C" void kernel_launch(void* const* d_in, const int* in_sizes, int n_in,
                              void* d_out, int out_size, void* d_ws, size_t ws_size,
                              hipStream_t stream) {
    const float* x   = (const float*)d_in[0];
    const float* Wq  = (const float*)d_in[1];
    const float* bq  = (const float*)d_in[2];
    const float* Wk  = (const float*)d_in[3];
    const float* bk  = (const float*)d_in[4];
    const float* Wv  = (const float*)d_in[5];
    const float* bv  = (const float*)d_in[6];
    const float* rpb = (const float*)d_in[7];
    const float* Wp  = (const float*)d_in[8];
    const float* bp  = (const float*)d_in[9];
    float* out = (float*)d_out;

    // workspace layout — bf16 intermediates; ~8.2 MB (xb eliminated)
    ushort* WpkT = (ushort*)d_ws;          // 81920
    ushort* WpT  = WpkT + 81920;           // 65536
    ushort* Ab   = WpT + 65536;            // 3211264
    ushort* Qb   = Ab + 3211264;           // 401408
    ushort* Kb   = Qb + BD * QK_PER_B;     // 401408
    ushort* Vb   = Kb + BD * QK_PER_B;     // 3211264
    float*  pb   = (float*)(Vb + BD * V_PER_B);  // 320

    prep_w<<<(81920 + 65536 + 320 + 255) / 256, 256, 0, stream>>>(
        Wq, Wk, Wv, bq, bk, bv, Wp, WpkT, WpT, pb);

    mfma_qkv<<<dim3(5, NROWS / 128), 256, 0, stream>>>(x, WpkT, pb, Qb, Kb, Vb);

    natten_attn4<<<dim3(7, 14, 32), 256, 0, stream>>>(Qb, Kb, Vb, rpb, Ab);

    mfma_out64<<<dim3(4, 196), 256, 0, stream>>>(Ab, WpT, bp, out);
}